// Round 6
// baseline (1096.997 us; speedup 1.0000x reference)
//
#include <hip/hip_runtime.h>
#include <hip/hip_bf16.h>

// GRU (TF GRUCell), B=2048, T=12, D=512, H=1024, fp32 in/out.
// R9: fuse the x-GEMM into the persistent step kernel. R8's counters showed
// gru_steps moving 845 MB HBM at 1.7 TB/s (= exactly its 497 us): the 151 MB
// Pg/Pc intermediate (write+read = 300 MB) pushed the footprint past the
// 256 MB LLC and evicted the weights every step. Now gates/cand GEMMs run
// K=1536 directly ([x_t | h(_r)] @ W): kt 0..3 stage x-part (xb + Bx),
// kt 4..11 stage h-part (hb/rhb + Bhg/Bhc). pre_gemm deleted. Same verified
// mT-local flag sync + bid%8 XCD mapping + sc0 staging as R8 (passed).
// hr-snapshot replaced by global hb read (R7-verified, kills 14.2M LDS
// conflicts); uS tile XOR-swizzled ((row>>2)&3) to 2-way (free).

#define T_SEQ 12
#define BATCH 2048
#define IND 512
#define HID 1024
#define NGATE (2 * HID)  // 2048
#define NPRE (NGATE + HID)

typedef __bf16 bf16x8 __attribute__((ext_vector_type(8)));
typedef __bf16 bf16x4 __attribute__((ext_vector_type(4)));
typedef float floatx4 __attribute__((ext_vector_type(4)));

#define AS1 __attribute__((address_space(1)))
#define AS3 __attribute__((address_space(3)))

__device__ __forceinline__ void gload16(const __bf16* g, __bf16* l) {
  __builtin_amdgcn_global_load_lds((const AS1 void*)g, (AS3 void*)l, 16, 0, 0);
}
// sc0 (L1-bypass) variant: for buffers mutated by other blocks on this XCD.
__device__ __forceinline__ void gload16c(const __bf16* g, __bf16* l) {
  __builtin_amdgcn_global_load_lds((const AS1 void*)g, (AS3 void*)l, 16, 0, 1);
}

__device__ __forceinline__ float fast_sigmoid(float v) {
  v = fminf(30.f, fmaxf(-30.f, v));
  return 1.f / (1.f + __expf(-v));
}
__device__ __forceinline__ float fast_tanh(float v) {
  v = fminf(15.f, fmaxf(-15.f, v));
  float e = __expf(2.f * v);
  return (e - 1.f) / (e + 1.f);
}

// ---- fused prep: weight pack + x fp32->bf16 + h init + ctr zero ----
__global__ __launch_bounds__(256) void prep(
    const float* __restrict__ Wg, const float* __restrict__ Wc,
    const float* __restrict__ x, const float* __restrict__ coded,
    __bf16* __restrict__ Bx, __bf16* __restrict__ Bhg, __bf16* __restrict__ Bhc,
    __bf16* __restrict__ xb, float* __restrict__ h32, __bf16* __restrict__ hb,
    unsigned* __restrict__ ctr) {
  int b = blockIdx.x;
  if (b < 2304) {
    int gid = b * 256 + threadIdx.x;
    int g = gid >> 6, lane = gid & 63;
    const float* W; int ld, row0, ksteps, wid; __bf16* out;
    if (g < 2048)      { W = Wg; ld = NGATE; row0 = 0;   ksteps = 16; wid = g;        out = Bx; }
    else if (g < 3072) { W = Wc; ld = HID;   row0 = 0;   ksteps = 16; wid = g - 2048; out = Bx + (size_t)2048 * 512; }
    else if (g < 7168) { W = Wg; ld = NGATE; row0 = IND; ksteps = 32; wid = g - 3072; out = Bhg; }
    else               { W = Wc; ld = HID;   row0 = IND; ksteps = 32; wid = g - 7168; out = Bhc; }
    int n16 = wid / ksteps, kt = wid - n16 * ksteps;
    int col = n16 * 16 + (lane & 15);
    int k0 = row0 + kt * 32 + (lane >> 4) * 8;
    bf16x8 v;
#pragma unroll
    for (int j = 0; j < 8; ++j) v[j] = (__bf16)W[(size_t)(k0 + j) * ld + col];
    *reinterpret_cast<bf16x8*>(out + (size_t)wid * 512 + lane * 8) = v;
  } else if (b < 4352) {
    int i = (b - 2304) * 256 + threadIdx.x;
    const float4* x4 = (const float4*)x;
    const int n4 = BATCH * T_SEQ * IND / 4;
    for (int k = i; k < n4; k += 2048 * 256) {
      float4 v = x4[k];
      bf16x4 o;
      o[0] = (__bf16)v.x; o[1] = (__bf16)v.y; o[2] = (__bf16)v.z; o[3] = (__bf16)v.w;
      *reinterpret_cast<bf16x4*>(xb + (size_t)k * 4) = o;
    }
  } else {
    int i = (b - 4352) * 256 + threadIdx.x;  // exactly BATCH*HID/4 threads
    if (b == 4352) {
#pragma unroll
      for (int j = 0; j < 4; ++j) ctr[threadIdx.x + j * 256] = 0u;
    }
    float4 v = ((const float4*)coded)[i];
    ((float4*)h32)[i] = v;
    bf16x4 o;
    o[0] = (__bf16)v.x; o[1] = (__bf16)v.y; o[2] = (__bf16)v.z; o[3] = (__bf16)v.w;
    *reinterpret_cast<bf16x4*>(hb + (size_t)i * 4) = o;
  }
}

// ---- persistent fused GRU: 512 blocks, 12 t, K=1536 GEMMs per phase ----
// bid: mT = (bid&7)*4 + ((bid>>3)&3) (16 blocks per mT, same XCD via bid%8
// round-robin); sub = bid>>5 in [0,16). Gate: 64 rows x 128 cols (r cols
// [sub*64,+64) U u cols [1024+sub*64,+64)), K = 512(x) + 1024(h). Cand:
// 64 x 64 cols [sub*64,+64), K = 512(x) + 1024(r*h). u stays in LDS.
// Sync: relaxed agent atomics; release via __syncthreads vmcnt(0) drain;
// mutable staging via sc0 (L2 = XCD coherence point).
__global__ __launch_bounds__(256, 2) void gru_steps(
    const __bf16* __restrict__ Bx, const __bf16* __restrict__ Bhg,
    const __bf16* __restrict__ Bhc, const __bf16* __restrict__ xb,
    const float* __restrict__ bg, const float* __restrict__ bc,
    float* __restrict__ h32, __bf16* __restrict__ hb,
    __bf16* __restrict__ rhb, float* __restrict__ out,
    unsigned* __restrict__ ctr) {
  __shared__ __bf16 Alds[64 * 128];  // 16 KB
  __shared__ __bf16 Blds[16384];     // 32 KB; [8192:] doubles as u-tile (fp32)
  float* uS = (float*)&Blds[8192];   // 64x64 fp32, live gate-epi -> cand-epi
  const int tid = threadIdx.x, lane = tid & 63, w = tid >> 6;
  const int wm = w >> 1, wn = w & 1, quad = lane >> 4, l16 = lane & 15;
  const int bid = blockIdx.x;
  const int mT = (bid & 7) * 4 + ((bid >> 3) & 3);
  const int sub = bid >> 5;
  unsigned* cG = ctr + mT * 16;
  unsigned* cC = ctr + 512 + mT * 16;

  // uS swizzle: spread quad-rows across banks (write & read use same map)
  auto uSi = [](int r, int c) { return r * 64 + (c ^ (((r >> 2) & 3) << 4)); };

  // A staging offsets: chunk c = tid+i*256, row=c>>4, ch=c&15 (inv-XOR src)
  int axOff[4], ahOff[4];
#pragma unroll
  for (int i = 0; i < 4; ++i) {
    int c = tid + i * 256, row = c >> 4, x8 = ((c & 15) ^ (row & 7)) * 8;
    axOff[i] = (mT * 64 + row) * (T_SEQ * IND) + x8;  // + t*512 + kt*128
    ahOff[i] = (mT * 64 + row) * HID + x8;            // + (kt-4)*128
  }
  // B staging bases (within-slice offset == tid*8 for packed layout)
  int bgx[8], bgh[8], bcx[4], bch[4];
#pragma unroll
  for (int i = 0; i < 8; ++i) {
    int n16g = (i < 4) ? (sub * 4 + i) : (64 + sub * 4 + (i - 4));
    bgx[i] = n16g * 8192 + tid * 8;    // Bx gate region; + kt*2048
    bgh[i] = n16g * 16384 + tid * 8;   // Bhg;            + (kt-4)*2048
  }
#pragma unroll
  for (int i = 0; i < 4; ++i) {
    int n16c = sub * 4 + i;
    bcx[i] = 2048 * 512 + n16c * 8192 + tid * 8;  // Bx cand region
    bch[i] = n16c * 16384 + tid * 8;              // Bhc
  }

  for (int t = 0; t < T_SEQ; ++t) {
    const int xT = t * 512;
    // ================= GATE: [x_t | h] @ Wg, K=1536 =================
    {
      floatx4 acc[2][4] = {};
      for (int kt = 0; kt < 12; ++kt) {
        __syncthreads();
        if (kt < 4) {
#pragma unroll
          for (int i = 0; i < 4; ++i)
            gload16(xb + axOff[i] + xT + kt * 128, Alds + (tid + i * 256) * 8);
#pragma unroll
          for (int i = 0; i < 8; ++i)
            gload16(Bx + bgx[i] + kt * 2048, Blds + (tid + i * 256) * 8);
        } else {
#pragma unroll
          for (int i = 0; i < 4; ++i)
            gload16c(hb + ahOff[i] + (kt - 4) * 128, Alds + (tid + i * 256) * 8);
#pragma unroll
          for (int i = 0; i < 8; ++i)
            gload16(Bhg + bgh[i] + (kt - 4) * 2048, Blds + (tid + i * 256) * 8);
        }
        __syncthreads();
#pragma unroll
        for (int ks2 = 0; ks2 < 4; ++ks2) {
          bf16x8 af[2], bfr[4];
#pragma unroll
          for (int mf = 0; mf < 2; ++mf) {
            int row = wm * 32 + mf * 16 + l16;
            af[mf] = *(const bf16x8*)&Alds[row * 128 + (((ks2 * 4 + quad) ^ (row & 7)) * 8)];
          }
#pragma unroll
          for (int nf = 0; nf < 4; ++nf)
            bfr[nf] = *(const bf16x8*)&Blds[(wn * 4 + nf) * 2048 + ks2 * 512 + lane * 8];
#pragma unroll
          for (int mf = 0; mf < 2; ++mf)
#pragma unroll
            for (int nf = 0; nf < 4; ++nf)
              acc[mf][nf] = __builtin_amdgcn_mfma_f32_16x16x32_bf16(af[mf], bfr[nf], acc[mf][nf], 0, 0, 0);
        }
      }
      const int colb = (wn * 16 + sub) * 64 + l16;
      float bgv[4];
#pragma unroll
      for (int nf = 0; nf < 4; ++nf) bgv[nf] = bg[colb + nf * 16];
#pragma unroll
      for (int mf = 0; mf < 2; ++mf) {
        int rowb = mT * 64 + wm * 32 + mf * 16 + quad * 4;
#pragma unroll
        for (int nf = 0; nf < 4; ++nf) {
#pragma unroll
          for (int i = 0; i < 4; ++i) {
            float s = fast_sigmoid(acc[mf][nf][i] + bgv[nf]);
            if (wn == 0) {
              size_t idx = (size_t)(rowb + i) * HID + sub * 64 + nf * 16 + l16;
              rhb[idx] = (__bf16)(s * (float)hb[idx]);
            } else {
              uS[uSi(wm * 32 + mf * 16 + quad * 4 + i, nf * 16 + l16)] = s;
            }
          }
        }
      }
    }
    __syncthreads();  // drains all waves' stores (vmcnt 0) + uS visible
    if (tid == 0) {
      __hip_atomic_fetch_add(cG, 1u, __ATOMIC_RELAXED, __HIP_MEMORY_SCOPE_AGENT);
      unsigned tgt = 16u * (t + 1);
      while (__hip_atomic_load(cG, __ATOMIC_RELAXED, __HIP_MEMORY_SCOPE_AGENT) < tgt)
        __builtin_amdgcn_s_sleep(2);
    }
    __syncthreads();
    // ================= CAND: [x_t | r*h] @ Wc, K=1536 =================
    {
      floatx4 acc[2][2] = {};
      for (int kt = 0; kt < 12; ++kt) {
        __syncthreads();
        if (kt < 4) {
#pragma unroll
          for (int i = 0; i < 4; ++i)
            gload16(xb + axOff[i] + xT + kt * 128, Alds + (tid + i * 256) * 8);
#pragma unroll
          for (int i = 0; i < 4; ++i)
            gload16(Bx + bcx[i] + kt * 2048, Blds + (tid + i * 256) * 8);
        } else {
#pragma unroll
          for (int i = 0; i < 4; ++i)
            gload16c(rhb + ahOff[i] + (kt - 4) * 128, Alds + (tid + i * 256) * 8);
#pragma unroll
          for (int i = 0; i < 4; ++i)
            gload16(Bhc + bch[i] + (kt - 4) * 2048, Blds + (tid + i * 256) * 8);
        }
        __syncthreads();
#pragma unroll
        for (int ks2 = 0; ks2 < 4; ++ks2) {
          bf16x8 af[2], bfr[2];
#pragma unroll
          for (int mf = 0; mf < 2; ++mf) {
            int row = wm * 32 + mf * 16 + l16;
            af[mf] = *(const bf16x8*)&Alds[row * 128 + (((ks2 * 4 + quad) ^ (row & 7)) * 8)];
          }
#pragma unroll
          for (int nf = 0; nf < 2; ++nf)
            bfr[nf] = *(const bf16x8*)&Blds[(wn * 2 + nf) * 2048 + ks2 * 512 + lane * 8];
#pragma unroll
          for (int mf = 0; mf < 2; ++mf)
#pragma unroll
            for (int nf = 0; nf < 2; ++nf)
              acc[mf][nf] = __builtin_amdgcn_mfma_f32_16x16x32_bf16(af[mf], bfr[nf], acc[mf][nf], 0, 0, 0);
        }
      }
#pragma unroll
      for (int mf = 0; mf < 2; ++mf) {
#pragma unroll
        for (int nf = 0; nf < 2; ++nf) {
          int col = sub * 64 + wn * 32 + nf * 16 + l16;
          float bcv = bc[col];
          int rowb = mT * 64 + wm * 32 + mf * 16 + quad * 4;
#pragma unroll
          for (int i = 0; i < 4; ++i) {
            float c = fast_tanh(acc[mf][nf][i] + bcv);
            size_t idx = (size_t)(rowb + i) * HID + col;
            float u = uS[uSi(wm * 32 + mf * 16 + quad * 4 + i, wn * 32 + nf * 16 + l16)];
            float hnew = u * h32[idx] + (1.f - u) * c;
            h32[idx] = hnew;
            hb[idx] = (__bf16)hnew;
            __builtin_nontemporal_store(hnew, &out[(size_t)(rowb + i) * (T_SEQ * HID) + t * HID + col]);
          }
        }
      }
    }
    __syncthreads();
    if (tid == 0) {
      __hip_atomic_fetch_add(cC, 1u, __ATOMIC_RELAXED, __HIP_MEMORY_SCOPE_AGENT);
      unsigned tgt = 16u * (t + 1);
      while (__hip_atomic_load(cC, __ATOMIC_RELAXED, __HIP_MEMORY_SCOPE_AGENT) < tgt)
        __builtin_amdgcn_s_sleep(2);
    }
    __syncthreads();
  }
}

extern "C" void kernel_launch(void* const* d_in, const int* in_sizes, int n_in,
                              void* d_out, int out_size, void* d_ws, size_t ws_size,
                              hipStream_t stream) {
  const float* x     = (const float*)d_in[0];
  const float* coded = (const float*)d_in[1];
  const float* Wg_f  = (const float*)d_in[2];
  const float* bg    = (const float*)d_in[3];
  const float* Wc_f  = (const float*)d_in[4];
  const float* bc    = (const float*)d_in[5];
  float* out = (float*)d_out;

  uintptr_t base = ((uintptr_t)d_ws + 255) & ~(uintptr_t)255;
  auto take = [&](size_t bytes) {
    void* p = (void*)base;
    base = (base + bytes + 255) & ~(uintptr_t)255;
    return p;
  };
  __bf16* Bx  = (__bf16*)take((size_t)(NPRE / 16) * 16 * 512 * 2);   // 3.1 MB
  __bf16* Bhg = (__bf16*)take((size_t)(NGATE / 16) * 32 * 512 * 2);  // 4.2 MB
  __bf16* Bhc = (__bf16*)take((size_t)(HID / 16) * 32 * 512 * 2);    // 2.1 MB
  __bf16* xb  = (__bf16*)take((size_t)BATCH * T_SEQ * IND * 2);      // 25.2 MB
  float*  h32 = (float*) take((size_t)BATCH * HID * 4);
  __bf16* hb  = (__bf16*)take((size_t)BATCH * HID * 2);
  __bf16* rhb = (__bf16*)take((size_t)BATCH * HID * 2);
  unsigned* ctr = (unsigned*)take(1024 * sizeof(unsigned));

  prep<<<6400, 256, 0, stream>>>(Wg_f, Wc_f, x, coded, Bx, Bhg, Bhc, xb, h32, hb, ctr);

  gru_steps<<<512, 256, 0, stream>>>(Bx, Bhg, Bhc, xb, bg, bc, h32, hb, rhb, out, ctr);
}